// Round 1
// baseline (1367.212 us; speedup 1.0000x reference)
//
#include <hip/hip_runtime.h>
#include <stdint.h>

// RPN proposal generation for MI355X (gfx950).
// Pipeline:
//   k_select: per (batch, level) exact top-K on objectness logits (3-pass radix
//             select on monotone float keys, stable ties), bitonic sort of the
//             selected <=1000 (gives the reference's per-level top_k rank =
//             concatenated position), decode+clip+minsize, XLA-bitwise sigmoid,
//             emit (probBits<<32 | ~pos) sort keys + clipped boxes to ws.
//   k_nms:    per batch: bitonic sort 8192 keys desc (prob desc, pos asc ==
//             reference argmax tie-break), then chunked greedy NMS (exact
//             equivalent of the 1000-step argmax/suppress scan), emit first
//             1000 kept (box, prob); pad with (0, -1e9).

#define NBATCH 16
#define KSUM 4768
#define NEGF -1e9f

struct Ptrs {
  const float* cls[5];
  const float* box[5];
  const float* anc;
};

__constant__ int c_hw[5]      = {65536, 16384, 4096, 1024, 256};
__constant__ int c_lghw[5]    = {16, 14, 12, 10, 8};
__constant__ int c_K[5]       = {1000, 1000, 1000, 1000, 768};
__constant__ int c_levNOff[5] = {0, 196608, 245760, 258048, 261120};
__constant__ int c_selOff[5]  = {0, 1000, 2000, 3000, 4000};

__device__ __forceinline__ unsigned int monokey(float f) {
  unsigned int u = __float_as_uint(f);
  return (u & 0x80000000u) ? ~u : (u | 0x80000000u);
}
__device__ __forceinline__ float inv_monokey(unsigned int k) {
  return __uint_as_float((k & 0x80000000u) ? (k ^ 0x80000000u) : ~k);
}

// Bitwise replica of XLA CPU logistic: 0.5 + 0.5 * fast_tanh(0.5*x).
// fast_tanh = Eigen/XLA rational approx, clamp +-7.90531110763549805 (no-FMA
// variant), |x| < 0.0004 -> x. Must NOT be FMA-contracted.
__device__ float sigmoid_xla(float x) {
  #pragma clang fp contract(off)
  float h = 0.5f * x;
  float hc = fminf(fmaxf(h, -7.90531110763549805f), 7.90531110763549805f);
  float x2 = hc * hc;
  float p = -2.76076847742355e-16f;
  p = p * x2 + 2.00018790482477e-13f;
  p = p * x2 + -8.60467152213735e-11f;
  p = p * x2 + 5.12229709037114e-08f;
  p = p * x2 + 1.48572235717979e-05f;
  p = p * x2 + 6.37261928875436e-04f;
  p = p * x2 + 4.89352455891786e-03f;
  p = hc * p;
  float q = 1.19825839466702e-06f;
  q = q * x2 + 1.18534705686654e-04f;
  q = q * x2 + 2.26843463243900e-03f;
  q = q * x2 + 4.89352518554385e-03f;
  float t = (fabsf(h) < 0.0004f) ? h : (p / q);
  return 0.5f + 0.5f * t;
}

__device__ void decode_box(float4 anc, float dx, float dy, float dw, float dh,
                           float& x0, float& y0, float& x1, float& y1, bool& keep) {
  #pragma clang fp contract(off)
  float aw = anc.z - anc.x;
  float ah = anc.w - anc.y;
  float ax = anc.x + 0.5f * aw;
  float ay = anc.y + 0.5f * ah;
  float dwc = fminf(dw, 4.135166556742356f);  // log(1000/16) rounded to f32
  float dhc = fminf(dh, 4.135166556742356f);
  float px = dx * aw + ax;
  float py = dy * ah + ay;
  float pw = expf(dwc) * aw;
  float ph = expf(dhc) * ah;
  x0 = px - 0.5f * pw;
  y0 = py - 0.5f * ph;
  x1 = px + 0.5f * pw;
  y1 = py + 0.5f * ph;
  x0 = fminf(fmaxf(x0, 0.0f), 1024.0f);
  y0 = fminf(fmaxf(y0, 0.0f), 1024.0f);
  x1 = fminf(fmaxf(x1, 0.0f), 1024.0f);
  y1 = fminf(fmaxf(y1, 0.0f), 1024.0f);
  keep = ((x1 - x0) >= 1.0f) && ((y1 - y0) >= 1.0f);
}

// Exact (iou > 0.7f) under IEEE f32 div, with safe fast paths: quotient<=0.65
// or >=0.75 cannot round across 0.7f.
__device__ __forceinline__ bool iou_gt(float4 a, float aa, float4 b, float ba) {
  #pragma clang fp contract(off)
  float ltx = fmaxf(a.x, b.x);
  float lty = fmaxf(a.y, b.y);
  float rbx = fminf(a.z, b.z);
  float rby = fminf(a.w, b.w);
  float w = fmaxf(rbx - ltx, 0.0f);
  float h = fmaxf(rby - lty, 0.0f);
  float inter = w * h;
  float denom = aa + ba - inter + 1e-9f;
  if (inter <= 0.65f * denom) return false;
  if (inter >= 0.75f * denom) return true;
  return (inter / denom) > 0.7f;
}

__global__ __launch_bounds__(256) void k_select(Ptrs p,
                                                unsigned long long* __restrict__ nmsKey,
                                                float4* __restrict__ boxesWs) {
  const int l = (int)(blockIdx.x % 5);
  const int b = (int)(blockIdx.x / 5);
  const int hw = c_hw[l];
  const int lghw = c_lghw[l];
  const int n = 3 * hw;
  const int K = c_K[l];
  const int tid = threadIdx.x;
  const float* base = p.cls[l] + (size_t)b * (size_t)n;
  const float4* base4 = (const float4*)base;
  const int n4 = n >> 2;

  __shared__ unsigned int hist[2048];
  __shared__ __align__(16) unsigned long long slots[1024];
  __shared__ unsigned int tieN[1024];
  __shared__ unsigned int sh[4];  // 0:bin 1:cum 2:selCnt 3:tieCnt

  for (int i = tid; i < 1024; i += 256) slots[i] = 0ULL;
  __syncthreads();

  if (K >= n) {
    // level 4: all elements selected; order fixed by the sort below.
    for (int i = tid; i < n; i += 256) {
      unsigned int mk = monokey(base[i]);
      int a = i >> lghw;
      int cell = i & (hw - 1);
      unsigned int nloc = (unsigned int)(cell * 3 + a);
      slots[i] = (((unsigned long long)mk) << 32) | (0xFFFFFFFFu - nloc);
    }
    __syncthreads();
  } else {
    // 3-pass radix select (11/11/10 bits) -> exact 32-bit K-th-largest key.
    unsigned int prefix = 0, cAbove = 0;
    for (int pass = 0; pass < 3; ++pass) {
      for (int i = tid; i < 2048; i += 256) hist[i] = 0u;
      __syncthreads();
      for (int i = tid; i < n4; i += 256) {
        float4 v = base4[i];
        float fv[4] = {v.x, v.y, v.z, v.w};
        #pragma unroll
        for (int c = 0; c < 4; ++c) {
          unsigned int mk = monokey(fv[c]);
          if (pass == 0) {
            atomicAdd(&hist[mk >> 21], 1u);
          } else if (pass == 1) {
            if ((mk >> 21) == prefix) atomicAdd(&hist[(mk >> 10) & 0x7FFu], 1u);
          } else {
            if ((mk >> 10) == prefix) atomicAdd(&hist[mk & 0x3FFu], 1u);
          }
        }
      }
      __syncthreads();
      if (tid == 0) {
        unsigned int c = cAbove;
        int nb = (pass == 2) ? 1024 : 2048;
        unsigned int t = 0;
        for (int i = nb - 1; i >= 0; --i) {
          if (c + hist[i] >= (unsigned int)K) { t = (unsigned int)i; break; }
          c += hist[i];
        }
        sh[0] = t; sh[1] = c;
      }
      __syncthreads();
      unsigned int t = sh[0];
      cAbove = sh[1];
      prefix = (pass == 0) ? t : ((prefix << ((pass == 2) ? 10 : 11)) | t);
    }
    const unsigned int threshKey = prefix;
    if (tid == 0) { sh[2] = 0u; sh[3] = 0u; }
    __syncthreads();
    // Selection pass: strictly-greater take slots; threshold-equal collected
    // for stable (lowest original index first) tie fill, matching lax.top_k.
    for (int i = tid; i < n4; i += 256) {
      float4 v = base4[i];
      float fv[4] = {v.x, v.y, v.z, v.w};
      #pragma unroll
      for (int c = 0; c < 4; ++c) {
        unsigned int mk = monokey(fv[c]);
        if (mk >= threshKey) {
          int pe = 4 * i + c;
          int a = pe >> lghw;
          int cell = pe & (hw - 1);
          unsigned int nloc = (unsigned int)(cell * 3 + a);
          if (mk > threshKey) {
            unsigned int s = atomicAdd(&sh[2], 1u);
            slots[s] = (((unsigned long long)mk) << 32) | (0xFFFFFFFFu - nloc);
          } else {
            unsigned int tt = atomicAdd(&sh[3], 1u);
            if (tt < 1024u) tieN[tt] = nloc;
          }
        }
      }
    }
    __syncthreads();
    if (tid == 0) {
      int cnt = (int)sh[2];
      int need = K - cnt;
      int tc = (int)sh[3];
      if (tc > 1024) tc = 1024;
      for (int s = 0; s < need; ++s) {
        unsigned int best = 0xFFFFFFFFu;
        int bj = -1;
        for (int i = 0; i < tc; ++i) {
          unsigned int v = tieN[i];
          if (v < best) { best = v; bj = i; }
        }
        if (bj < 0) break;
        tieN[bj] = 0xFFFFFFFFu;
        slots[cnt + s] = (((unsigned long long)threshKey) << 32) | (0xFFFFFFFFu - best);
      }
    }
    __syncthreads();
  }

  // Bitonic sort slots[1024] descending by (logitKey desc, nloc asc).
  for (int kk = 2; kk <= 1024; kk <<= 1) {
    for (int j = kk >> 1; j > 0; j >>= 1) {
      for (int i = tid; i < 1024; i += 256) {
        int partner = i ^ j;
        if (partner > i) {
          unsigned long long x = slots[i];
          unsigned long long y = slots[partner];
          bool descDir = ((i & kk) == 0);
          if (descDir ? (x < y) : (x > y)) { slots[i] = y; slots[partner] = x; }
        }
      }
      __syncthreads();
    }
  }

  // Decode + sigmoid + emit NMS keys; rank r == reference top_k rank.
  const float4* anc4 = (const float4*)p.anc;
  const float* bxbase = p.box[l];
  const int levN = c_levNOff[l];
  const int selO = c_selOff[l];
  for (int r = tid; r < K; r += 256) {
    unsigned long long e = slots[r];
    int pos = selO + r;
    size_t o = (size_t)b * KSUM + (size_t)pos;
    if (e == 0ULL) {  // cannot happen with well-formed data; OOB guard
      nmsKey[o] = 0ULL;
      boxesWs[o] = make_float4(0.f, 0.f, 0.f, 0.f);
      continue;
    }
    unsigned int mk = (unsigned int)(e >> 32);
    unsigned int nloc = 0xFFFFFFFFu - (unsigned int)(e & 0xFFFFFFFFull);
    float logit = inv_monokey(mk);
    int cell = (int)(nloc / 3u);
    int a = (int)(nloc - 3u * (unsigned int)cell);
    const float* dptr = bxbase + (((size_t)(b * 12 + a * 4)) << lghw) + (size_t)cell;
    float dx = dptr[0];
    float dy = dptr[(size_t)hw];
    float dw = dptr[(size_t)2 * (size_t)hw];
    float dh = dptr[(size_t)3 * (size_t)hw];
    float4 anc = anc4[levN + (int)nloc];
    float x0, y0, x1, y1;
    bool keep;
    decode_box(anc, dx, dy, dw, dh, x0, y0, x1, y1, keep);
    float prob = sigmoid_xla(logit);
    unsigned long long key =
        keep ? ((((unsigned long long)__float_as_uint(prob)) << 32) |
                (0xFFFFFFFFu - (unsigned int)pos))
             : 0ULL;
    nmsKey[o] = key;
    boxesWs[o] = make_float4(x0, y0, x1, y1);
  }
}

__global__ __launch_bounds__(256) void k_nms(const unsigned long long* __restrict__ nmsKey,
                                             const float4* __restrict__ boxesWs,
                                             float* __restrict__ out) {
  const int b = blockIdx.x;
  const int tid = threadIdx.x;
  __shared__ __align__(16) unsigned long long keys[8192];  // 64 KiB

  // Phase-2 arrays overlay keys[4768..8191] (zeros-only after the sort).
  char* ovl = (char*)&keys[4768];                       // 38144 B offset, 16-aligned
  float4* keptBox = (float4*)(ovl);                     // 16000 B
  float* keptArea = (float*)(ovl + 16000);              //  4000 B
  float4* chunkBox = (float4*)(ovl + 20000);            //  2048 B
  float* chunkArea = (float*)(ovl + 22048);             //   512 B
  float* chunkProb = (float*)(ovl + 22560);             //   512 B
  unsigned int* chunkAlive = (unsigned int*)(ovl + 23072);            // 512 B
  unsigned long long* masks = (unsigned long long*)(ovl + 23584);     // 2048 B
  unsigned long long* sAB = (unsigned long long*)(ovl + 25632);       // 16 B

  for (int i = tid; i < 8192; i += 256)
    keys[i] = (i < KSUM) ? nmsKey[(size_t)b * KSUM + i] : 0ULL;
  __syncthreads();

  // Bitonic sort 8192 desc: (probBits desc, pos asc) == reference argmax order.
  for (int kk = 2; kk <= 8192; kk <<= 1) {
    for (int j = kk >> 1; j > 0; j >>= 1) {
      for (int i = tid; i < 8192; i += 256) {
        int partner = i ^ j;
        if (partner > i) {
          unsigned long long x = keys[i];
          unsigned long long y = keys[partner];
          bool descDir = ((i & kk) == 0);
          if (descDir ? (x < y) : (x > y)) { keys[i] = y; keys[partner] = x; }
        }
      }
      __syncthreads();
    }
  }

  // Chunked greedy NMS: exact equivalent of the 1000-step argmax/suppress scan.
  int m = 0;  // kept so far (uniform across block)
  for (int cs = 0; cs < KSUM && m < 1000; cs += 128) {
    if (tid < 128) {
      int idx = cs + tid;
      unsigned long long e = (idx < KSUM) ? keys[idx] : 0ULL;
      float4 bx = make_float4(0.f, 0.f, 0.f, 0.f);
      float ar = 0.f, pr = 0.f;
      unsigned int alive = 0u;
      if (e != 0ULL) {
        unsigned int r = 0xFFFFFFFFu - (unsigned int)(e & 0xFFFFFFFFull);
        bx = boxesWs[(size_t)b * KSUM + r];
        pr = __uint_as_float((unsigned int)(e >> 32));
        {
          #pragma clang fp contract(off)
          ar = (bx.z - bx.x) * (bx.w - bx.y);
        }
        alive = 1u;
      }
      chunkBox[tid] = bx;
      chunkArea[tid] = ar;
      chunkProb[tid] = pr;
      chunkAlive[tid] = alive;
      masks[tid * 2] = 0ULL;
      masks[tid * 2 + 1] = 0ULL;
    }
    __syncthreads();

    // A: suppress chunk boxes vs already-kept list (2 threads per box).
    {
      int i0 = tid & 127;
      int half = tid >> 7;
      float4 my = chunkBox[i0];
      float myA = chunkArea[i0];
      bool supp = false;
      for (int i = half; i < m; i += 2)
        supp = supp || iou_gt(keptBox[i], keptArea[i], my, myA);
      if (supp) chunkAlive[i0] = 0u;
    }
    __syncthreads();

    // B: intra-chunk suppression masks (mask[j] = later boxes j suppresses).
    for (int pI = tid; pI < 128 * 128; pI += 256) {
      int i = pI >> 7;   // later box
      int j = pI & 127;  // earlier box
      if (j < i) {
        if (iou_gt(chunkBox[j], chunkArea[j], chunkBox[i], chunkArea[i]))
          atomicOr(&masks[j * 2 + (i >> 6)], 1ULL << (i & 63));
      }
    }
    __syncthreads();

    // C: serial greedy resolution on 128-bit alive mask.
    {
      unsigned long long bal = __ballot((tid < 128) && (chunkAlive[tid] != 0u));
      if (tid == 0) sAB[0] = bal;
      if (tid == 64) sAB[1] = bal;
    }
    __syncthreads();
    if (tid == 0) {
      unsigned long long A0 = sAB[0], A1 = sAB[1];
      for (int k = 0; k < 128; ++k) {
        bool al = (k < 64) ? ((A0 >> k) & 1ULL) : ((A1 >> (k - 64)) & 1ULL);
        if (al) {
          A0 &= ~masks[k * 2];
          A1 &= ~masks[k * 2 + 1];
        }
      }
      sAB[0] = A0;
      sAB[1] = A1;
    }
    __syncthreads();

    // D: emit kept boxes in order, append to kept list.
    unsigned long long A0 = sAB[0], A1 = sAB[1];
    int total = __popcll(A0) + __popcll(A1);
    if (tid < 128) {
      bool kept = (tid < 64) ? ((A0 >> tid) & 1ULL) : ((A1 >> (tid - 64)) & 1ULL);
      if (kept) {
        int rank = (tid < 64)
                       ? __popcll(A0 & ((1ULL << tid) - 1ULL))
                       : (__popcll(A0) + __popcll(A1 & ((1ULL << (tid - 64)) - 1ULL)));
        int g = m + rank;
        if (g < 1000) {
          keptBox[g] = chunkBox[tid];
          keptArea[g] = chunkArea[tid];
          ((float4*)out)[b * 1000 + g] = chunkBox[tid];
          out[64000 + b * 1000 + g] = chunkProb[tid];
        }
      }
    }
    m += total;
    if (m > 1000) m = 1000;
    __syncthreads();
  }

  // Pad: box = 0, score = NEG (reference's invalid-pick output).
  for (int g = m + tid; g < 1000; g += 256) {
    ((float4*)out)[b * 1000 + g] = make_float4(0.f, 0.f, 0.f, 0.f);
    out[64000 + b * 1000 + g] = NEGF;
  }
}

extern "C" void kernel_launch(void* const* d_in, const int* in_sizes, int n_in,
                              void* d_out, int out_size, void* d_ws, size_t ws_size,
                              hipStream_t stream) {
  // setup_inputs dict order is interleaved (cls0,box0,cls1,box1,...,anchors);
  // detect defensively in case the harness uses signature order instead.
  bool interleaved = (in_sizes[1] == 16 * 12 * 256 * 256);
  Ptrs p;
  for (int l = 0; l < 5; ++l) {
    p.cls[l] = (const float*)d_in[interleaved ? (2 * l) : l];
    p.box[l] = (const float*)d_in[interleaved ? (2 * l + 1) : (5 + l)];
  }
  p.anc = (const float*)d_in[10];

  unsigned long long* nmsKey = (unsigned long long*)d_ws;
  float4* boxesWs = (float4*)((char*)d_ws + (size_t)NBATCH * KSUM * 8);

  k_select<<<dim3(NBATCH * 5), dim3(256), 0, stream>>>(p, nmsKey, boxesWs);
  k_nms<<<dim3(NBATCH), dim3(256), 0, stream>>>(nmsKey, boxesWs, (float*)d_out);
}

// Round 2
// 370.226 us; speedup vs baseline: 3.6929x; 3.6929x over previous
//
#include <hip/hip_runtime.h>
#include <stdint.h>

// RPN proposal generation for MI355X (gfx950) — round 2.
// vs R1: removed the three latency-serialization hotspots identified by
// rocprof (VALUBusy 1%, Occ 0.7%):
//  - k_select threshold scan: serial break-loop -> parallel suffix scan
//  - k_nms phase C: serial tid0 resolution -> wave-ballot two-stage resolve
//  - k_nms phase A: short-circuit || -> pipelined |=, 8 threads/box
//  - both kernels: 256 -> 1024 threads/block

#define NBATCH 16
#define KSUM 4768
#define NEGF -1e9f

struct Ptrs {
  const float* cls[5];
  const float* box[5];
  const float* anc;
};

__constant__ int c_hw[5]      = {65536, 16384, 4096, 1024, 256};
__constant__ int c_lghw[5]    = {16, 14, 12, 10, 8};
__constant__ int c_K[5]       = {1000, 1000, 1000, 1000, 768};
__constant__ int c_levNOff[5] = {0, 196608, 245760, 258048, 261120};
__constant__ int c_selOff[5]  = {0, 1000, 2000, 3000, 4000};

__device__ __forceinline__ unsigned int monokey(float f) {
  unsigned int u = __float_as_uint(f);
  return (u & 0x80000000u) ? ~u : (u | 0x80000000u);
}
__device__ __forceinline__ float inv_monokey(unsigned int k) {
  return __uint_as_float((k & 0x80000000u) ? (k ^ 0x80000000u) : ~k);
}

// Bitwise replica of XLA CPU logistic: 0.5 + 0.5 * fast_tanh(0.5*x). Verified
// bit-exact in R1 (absmax 0.0). Must NOT be FMA-contracted.
__device__ float sigmoid_xla(float x) {
  #pragma clang fp contract(off)
  float h = 0.5f * x;
  float hc = fminf(fmaxf(h, -7.90531110763549805f), 7.90531110763549805f);
  float x2 = hc * hc;
  float p = -2.76076847742355e-16f;
  p = p * x2 + 2.00018790482477e-13f;
  p = p * x2 + -8.60467152213735e-11f;
  p = p * x2 + 5.12229709037114e-08f;
  p = p * x2 + 1.48572235717979e-05f;
  p = p * x2 + 6.37261928875436e-04f;
  p = p * x2 + 4.89352455891786e-03f;
  p = hc * p;
  float q = 1.19825839466702e-06f;
  q = q * x2 + 1.18534705686654e-04f;
  q = q * x2 + 2.26843463243900e-03f;
  q = q * x2 + 4.89352518554385e-03f;
  float t = (fabsf(h) < 0.0004f) ? h : (p / q);
  return 0.5f + 0.5f * t;
}

__device__ void decode_box(float4 anc, float dx, float dy, float dw, float dh,
                           float& x0, float& y0, float& x1, float& y1, bool& keep) {
  #pragma clang fp contract(off)
  float aw = anc.z - anc.x;
  float ah = anc.w - anc.y;
  float ax = anc.x + 0.5f * aw;
  float ay = anc.y + 0.5f * ah;
  float dwc = fminf(dw, 4.135166556742356f);
  float dhc = fminf(dh, 4.135166556742356f);
  float px = dx * aw + ax;
  float py = dy * ah + ay;
  float pw = expf(dwc) * aw;
  float ph = expf(dhc) * ah;
  x0 = px - 0.5f * pw;
  y0 = py - 0.5f * ph;
  x1 = px + 0.5f * pw;
  y1 = py + 0.5f * ph;
  x0 = fminf(fmaxf(x0, 0.0f), 1024.0f);
  y0 = fminf(fmaxf(y0, 0.0f), 1024.0f);
  x1 = fminf(fmaxf(x1, 0.0f), 1024.0f);
  y1 = fminf(fmaxf(y1, 0.0f), 1024.0f);
  keep = ((x1 - x0) >= 1.0f) && ((y1 - y0) >= 1.0f);
}

// Exact (inter/denom > 0.7f) under IEEE f32 div; one cheap early-out (a
// quotient <= 0.65 cannot round across 0.7f).
__device__ __forceinline__ bool iou_gt(float4 a, float aa, float4 b, float ba) {
  #pragma clang fp contract(off)
  float w = fmaxf(fminf(a.z, b.z) - fmaxf(a.x, b.x), 0.0f);
  float h = fmaxf(fminf(a.w, b.w) - fmaxf(a.y, b.y), 0.0f);
  float inter = w * h;
  float denom = aa + ba - inter + 1e-9f;
  if (inter <= 0.65f * denom) return false;
  return (inter / denom) > 0.7f;
}

__global__ __launch_bounds__(1024) void k_select(Ptrs p,
                                                 unsigned long long* __restrict__ nmsKey,
                                                 float4* __restrict__ boxesWs) {
  const int l = (int)(blockIdx.x % 5);
  const int b = (int)(blockIdx.x / 5);
  const int hw = c_hw[l];
  const int lghw = c_lghw[l];
  const int n = 3 * hw;
  const int K = c_K[l];
  const int tid = threadIdx.x;
  const float* base = p.cls[l] + (size_t)b * (size_t)n;
  const float4* base4 = (const float4*)base;
  const int n4 = n >> 2;

  __shared__ unsigned int histF[8192];  // 4 copies x 2048 bins (atomic fan-out)
  __shared__ __align__(16) unsigned long long slots[1024];
  __shared__ unsigned int tieN[1024];
  __shared__ unsigned int sh[4];  // 0:bin 1:cum 2:selCnt 3:tieCnt
  __shared__ unsigned int wsum[16];
  __shared__ unsigned int wsuf[17];

  slots[tid] = 0ULL;

  if (K >= n) {
    // level 4: all elements selected; order fixed by the sort below.
    if (tid < n) {
      unsigned int mk = monokey(base[tid]);
      int a = tid >> lghw;
      int cell = tid & (hw - 1);
      unsigned int nloc = (unsigned int)(cell * 3 + a);
      slots[tid] = (((unsigned long long)mk) << 32) | (0xFFFFFFFFu - nloc);
    }
    __syncthreads();
  } else {
    // 3-pass radix select (11/11/10 bits) -> exact 32-bit K-th-largest key.
    unsigned int prefix = 0, cAbove = 0;
    const int lane = tid & 63;
    const int w = tid >> 6;
    const int copy = (tid >> 6) & 3;
    unsigned int* hc = &histF[copy * 2048];
    for (int pass = 0; pass < 3; ++pass) {
      for (int i = tid; i < 8192; i += 1024) histF[i] = 0u;
      __syncthreads();
      for (int i = tid; i < n4; i += 1024) {
        float4 v = base4[i];
        float fv[4] = {v.x, v.y, v.z, v.w};
        #pragma unroll
        for (int c = 0; c < 4; ++c) {
          unsigned int mk = monokey(fv[c]);
          if (pass == 0) {
            atomicAdd(&hc[mk >> 21], 1u);
          } else if (pass == 1) {
            if ((mk >> 21) == prefix) atomicAdd(&hc[(mk >> 10) & 0x7FFu], 1u);
          } else {
            if ((mk >> 10) == prefix) atomicAdd(&hc[mk & 0x3FFu], 1u);
          }
        }
      }
      __syncthreads();
      // Parallel threshold find: per-thread bin group -> intra-wave inclusive
      // suffix scan (shfl) -> wave totals -> global suffix -> crossing test.
      const int nb = (pass == 2) ? 1024 : 2048;
      unsigned int h0, h1;
      if (nb == 2048) {
        int b0 = 2 * tid, b1 = 2 * tid + 1;
        h0 = histF[b0] + histF[2048 + b0] + histF[4096 + b0] + histF[6144 + b0];
        h1 = histF[b1] + histF[2048 + b1] + histF[4096 + b1] + histF[6144 + b1];
      } else {
        h0 = histF[tid] + histF[2048 + tid] + histF[4096 + tid] + histF[6144 + tid];
        h1 = 0u;
      }
      unsigned int x = h0 + h1;
      #pragma unroll
      for (int off = 1; off < 64; off <<= 1) {
        unsigned int v = __shfl_down(x, off);
        if (lane + off < 64) x += v;
      }
      if (lane == 0) wsum[w] = x;
      __syncthreads();
      if (tid == 0) {
        unsigned int acc = 0;
        wsuf[16] = 0u;
        for (int q = 15; q >= 0; --q) { acc += wsum[q]; wsuf[q] = acc; }
      }
      __syncthreads();
      unsigned int SUF0 = x + wsuf[w + 1];  // inclusive suffix of thread's 1st bin
      unsigned int Ku = (unsigned int)K;
      if (cAbove + SUF0 >= Ku && cAbove + SUF0 - h0 < Ku) {
        sh[0] = (nb == 2048) ? (unsigned int)(2 * tid) : (unsigned int)tid;
        sh[1] = cAbove + SUF0 - h0;
      }
      if (nb == 2048) {
        unsigned int SUF1 = SUF0 - h0;
        if (cAbove + SUF1 >= Ku && cAbove + SUF1 - h1 < Ku) {
          sh[0] = (unsigned int)(2 * tid + 1);
          sh[1] = cAbove + SUF1 - h1;
        }
      }
      __syncthreads();
      unsigned int t = sh[0];
      cAbove = sh[1];
      prefix = (pass == 0) ? t : ((prefix << ((pass == 2) ? 10 : 11)) | t);
    }
    const unsigned int threshKey = prefix;
    if (tid == 0) { sh[2] = 0u; sh[3] = 0u; }
    __syncthreads();
    // Selection pass: strictly-greater take slots; threshold-equal collected
    // for stable (lowest original index first) tie fill, matching lax.top_k.
    for (int i = tid; i < n4; i += 1024) {
      float4 v = base4[i];
      float fv[4] = {v.x, v.y, v.z, v.w};
      #pragma unroll
      for (int c = 0; c < 4; ++c) {
        unsigned int mk = monokey(fv[c]);
        if (mk >= threshKey) {
          int pe = 4 * i + c;
          int a = pe >> lghw;
          int cell = pe & (hw - 1);
          unsigned int nloc = (unsigned int)(cell * 3 + a);
          if (mk > threshKey) {
            unsigned int s = atomicAdd(&sh[2], 1u);
            slots[s] = (((unsigned long long)mk) << 32) | (0xFFFFFFFFu - nloc);
          } else {
            unsigned int tt = atomicAdd(&sh[3], 1u);
            if (tt < 1024u) tieN[tt] = nloc;
          }
        }
      }
    }
    __syncthreads();
    if (tid == 0) {  // tie fill: `need` is typically 1-3; serial is fine
      int cnt = (int)sh[2];
      int need = K - cnt;
      int tc = (int)sh[3];
      if (tc > 1024) tc = 1024;
      for (int s = 0; s < need; ++s) {
        unsigned int best = 0xFFFFFFFFu;
        int bj = -1;
        for (int i = 0; i < tc; ++i) {
          unsigned int v = tieN[i];
          if (v < best) { best = v; bj = i; }
        }
        if (bj < 0) break;
        tieN[bj] = 0xFFFFFFFFu;
        slots[cnt + s] = (((unsigned long long)threshKey) << 32) | (0xFFFFFFFFu - best);
      }
    }
    __syncthreads();
  }

  // Bitonic sort slots[1024] descending by (logitKey desc, nloc asc).
  for (int kk = 2; kk <= 1024; kk <<= 1) {
    for (int j = kk >> 1; j > 0; j >>= 1) {
      int i = tid;
      int partner = i ^ j;
      if (partner > i) {
        unsigned long long x = slots[i];
        unsigned long long y = slots[partner];
        bool descDir = ((i & kk) == 0);
        if (descDir ? (x < y) : (x > y)) { slots[i] = y; slots[partner] = x; }
      }
      __syncthreads();
    }
  }

  // Decode + sigmoid + emit NMS keys; rank r == reference top_k rank.
  const float4* anc4 = (const float4*)p.anc;
  const float* bxbase = p.box[l];
  const int levN = c_levNOff[l];
  const int selO = c_selOff[l];
  if (tid < K) {
    int r = tid;
    unsigned long long e = slots[r];
    int pos = selO + r;
    size_t o = (size_t)b * KSUM + (size_t)pos;
    if (e == 0ULL) {
      nmsKey[o] = 0ULL;
      boxesWs[o] = make_float4(0.f, 0.f, 0.f, 0.f);
    } else {
      unsigned int mk = (unsigned int)(e >> 32);
      unsigned int nloc = 0xFFFFFFFFu - (unsigned int)(e & 0xFFFFFFFFull);
      float logit = inv_monokey(mk);
      int cell = (int)(nloc / 3u);
      int a = (int)(nloc - 3u * (unsigned int)cell);
      const float* dptr = bxbase + (((size_t)(b * 12 + a * 4)) << lghw) + (size_t)cell;
      float dx = dptr[0];
      float dy = dptr[(size_t)hw];
      float dw = dptr[(size_t)2 * (size_t)hw];
      float dh = dptr[(size_t)3 * (size_t)hw];
      float4 anc = anc4[levN + (int)nloc];
      float x0, y0, x1, y1;
      bool keep;
      decode_box(anc, dx, dy, dw, dh, x0, y0, x1, y1, keep);
      float prob = sigmoid_xla(logit);
      unsigned long long key =
          keep ? ((((unsigned long long)__float_as_uint(prob)) << 32) |
                  (0xFFFFFFFFu - (unsigned int)pos))
               : 0ULL;
      nmsKey[o] = key;
      boxesWs[o] = make_float4(x0, y0, x1, y1);
    }
  }
}

__global__ __launch_bounds__(1024) void k_nms(const unsigned long long* __restrict__ nmsKey,
                                              const float4* __restrict__ boxesWs,
                                              float* __restrict__ out) {
  const int b = blockIdx.x;
  const int tid = threadIdx.x;
  __shared__ __align__(16) unsigned long long keys[8192];  // 64 KiB

  // Phase-2 arrays overlay keys[4768..8191] (zeros-only after the sort).
  char* ovl = (char*)&keys[4768];                        // byte 38144, 16-aligned
  float4* keptBox = (float4*)(ovl);                      // 16000 B
  float4* chunkBox = (float4*)(ovl + 16000);             //  2048 B
  float* chunkArea = (float*)(ovl + 18048);              //   512 B
  float* chunkProb = (float*)(ovl + 18560);              //   512 B
  unsigned int* chunkAlive = (unsigned int*)(ovl + 19072);         // 512 B
  unsigned long long* suppBy = (unsigned long long*)(ovl + 19584); // 2048 B (col masks)
  unsigned long long* sAB = (unsigned long long*)(ovl + 21632);    // 16 B

  for (int i = tid; i < 8192; i += 1024)
    keys[i] = (i < KSUM) ? nmsKey[(size_t)b * KSUM + i] : 0ULL;
  __syncthreads();

  // Bitonic sort 8192 desc: (probBits desc, pos asc) == reference argmax order.
  // Pair-enumerated: 4096 compare-exchanges per stage, 4 per thread.
  for (int kk = 2; kk <= 8192; kk <<= 1) {
    for (int j = kk >> 1; j > 0; j >>= 1) {
      #pragma unroll 4
      for (int pp = tid; pp < 4096; pp += 1024) {
        int low = pp & (j - 1);
        int i = ((pp - low) << 1) | low;
        int pr = i | j;
        unsigned long long x = keys[i];
        unsigned long long y = keys[pr];
        bool descDir = ((i & kk) == 0);
        if (descDir ? (x < y) : (x > y)) { keys[i] = y; keys[pr] = x; }
      }
      __syncthreads();
    }
  }

  // Chunked greedy NMS: exact equivalent of the 1000-step argmax/suppress scan.
  int m = 0;  // kept so far (uniform across block)
  for (int cs = 0; cs < KSUM && m < 1000; cs += 128) {
    // init chunk
    if (tid < 128) {
      int idx = cs + tid;
      unsigned long long e = (idx < KSUM) ? keys[idx] : 0ULL;
      float4 bx = make_float4(0.f, 0.f, 0.f, 0.f);
      float ar = 0.f, pr = 0.f;
      unsigned int alive = 0u;
      if (e != 0ULL) {
        unsigned int r = 0xFFFFFFFFu - (unsigned int)(e & 0xFFFFFFFFull);
        bx = boxesWs[(size_t)b * KSUM + r];
        pr = __uint_as_float((unsigned int)(e >> 32));
        {
          #pragma clang fp contract(off)
          ar = (bx.z - bx.x) * (bx.w - bx.y);
        }
        alive = 1u;
      }
      chunkBox[tid] = bx;
      chunkArea[tid] = ar;
      chunkProb[tid] = pr;
      chunkAlive[tid] = alive;
    }
    if (tid < 256) suppBy[tid] = 0ULL;
    __syncthreads();

    // A: suppress chunk boxes vs already-kept list (8 threads per box; no
    // short-circuit so loads pipeline; keptBox reads are wave-broadcast).
    {
      int i0 = tid & 127;
      int sl = tid >> 7;  // 0..7
      float4 my = chunkBox[i0];
      float myA = chunkArea[i0];
      bool supp = false;
      #pragma unroll 4
      for (int i = sl; i < m; i += 8) {
        float4 kb = keptBox[i];
        float ka;
        {
          #pragma clang fp contract(off)
          ka = (kb.z - kb.x) * (kb.w - kb.y);
        }
        supp = supp | iou_gt(kb, ka, my, myA);
      }
      if (supp) chunkAlive[i0] = 0u;
    }
    // B: intra-chunk column masks: suppBy[i] bit j == (j<i && iou(j,i)>thr).
    for (int pI = tid; pI < 16384; pI += 1024) {
      int i = pI >> 7;   // later box
      int j = pI & 127;  // earlier box
      if (j < i) {
        if (iou_gt(chunkBox[j], chunkArea[j], chunkBox[i], chunkArea[i]))
          atomicOr(&suppBy[i * 2 + (j >> 6)], 1ULL << (j & 63));
      }
    }
    __syncthreads();

    // C: wave-ballot greedy resolution (wave 0), two 64-box halves + cross.
    if (tid < 64) {
      int lane = tid;
      bool aliveLo = chunkAlive[lane] != 0u;
      bool aliveHi = chunkAlive[64 + lane] != 0u;
      unsigned long long sLL = suppBy[lane * 2];
      unsigned long long sHL = suppBy[(64 + lane) * 2];
      unsigned long long sHH = suppBy[(64 + lane) * 2 + 1];
      for (int k = 0; k < 64; ++k) {
        unsigned long long A = __ballot(aliveLo);
        if (((A >> k) & 1ULL) && ((sLL >> k) & 1ULL)) aliveLo = false;
      }
      unsigned long long A0 = __ballot(aliveLo);
      if (sHL & A0) aliveHi = false;
      for (int k = 0; k < 64; ++k) {
        unsigned long long Bm = __ballot(aliveHi);
        if (((Bm >> k) & 1ULL) && ((sHH >> k) & 1ULL)) aliveHi = false;
      }
      unsigned long long A1 = __ballot(aliveHi);
      if (lane == 0) { sAB[0] = A0; sAB[1] = A1; }
    }
    __syncthreads();

    // D: emit kept boxes in order, append to kept list.
    unsigned long long A0 = sAB[0], A1 = sAB[1];
    int total = __popcll(A0) + __popcll(A1);
    if (tid < 128) {
      bool kept = (tid < 64) ? ((A0 >> tid) & 1ULL) : ((A1 >> (tid - 64)) & 1ULL);
      if (kept) {
        int rank = (tid < 64)
                       ? __popcll(A0 & ((1ULL << tid) - 1ULL))
                       : (__popcll(A0) + __popcll(A1 & ((1ULL << (tid - 64)) - 1ULL)));
        int g = m + rank;
        if (g < 1000) {
          keptBox[g] = chunkBox[tid];
          ((float4*)out)[b * 1000 + g] = chunkBox[tid];
          out[64000 + b * 1000 + g] = chunkProb[tid];
        }
      }
    }
    m += total;
    if (m > 1000) m = 1000;
    __syncthreads();
  }

  // Pad: box = 0, score = NEG (reference's invalid-pick output).
  for (int g = m + tid; g < 1000; g += 1024) {
    ((float4*)out)[b * 1000 + g] = make_float4(0.f, 0.f, 0.f, 0.f);
    out[64000 + b * 1000 + g] = NEGF;
  }
}

extern "C" void kernel_launch(void* const* d_in, const int* in_sizes, int n_in,
                              void* d_out, int out_size, void* d_ws, size_t ws_size,
                              hipStream_t stream) {
  bool interleaved = (in_sizes[1] == 16 * 12 * 256 * 256);
  Ptrs p;
  for (int l = 0; l < 5; ++l) {
    p.cls[l] = (const float*)d_in[interleaved ? (2 * l) : l];
    p.box[l] = (const float*)d_in[interleaved ? (2 * l + 1) : (5 + l)];
  }
  p.anc = (const float*)d_in[10];

  unsigned long long* nmsKey = (unsigned long long*)d_ws;
  float4* boxesWs = (float4*)((char*)d_ws + (size_t)NBATCH * KSUM * 8);

  k_select<<<dim3(NBATCH * 5), dim3(1024), 0, stream>>>(p, nmsKey, boxesWs);
  k_nms<<<dim3(NBATCH), dim3(1024), 0, stream>>>(nmsKey, boxesWs, (float*)d_out);
}

// Round 3
// 250.133 us; speedup vs baseline: 5.4659x; 1.4801x over previous
//
#include <hip/hip_runtime.h>
#include <stdint.h>

// RPN proposal generation for MI355X (gfx950) — round 3.
// vs R2 (370 us; k_nms 245 us dominated by the 8192 bitonic's 91 barrier
// substeps; k_select by 4 full global scans + 55-substep bitonic):
//  - k_nms: 8192-bitonic REPLACED by 5-way merge via rank-by-binary-search
//    (per-level segments are already sorted in NMS order; compaction in
//    k_select removes keep=false zeros so segments are strictly sorted).
//  - k_select: pass-1 candidate capture into LDS -> passes 2+selection run
//    over <=4096 LDS candidates instead of global re-scans (fallback kept).
//  - k_select: 1024-bitonic now hybrid: intra-wave stages via shfl_xor (no
//    barrier), only j>=64 stages through LDS (10 vs 55 barrier substeps).
//  - k_nms phase C: iterate only set bits of the suppressor union mask.

#define NBATCH 16
#define KSUM 4768
#define NEGF -1e9f
#define CANDCAP 4096
typedef unsigned long long u64;
typedef unsigned int u32;

struct Ptrs {
  const float* cls[5];
  const float* box[5];
  const float* anc;
};

__constant__ int c_hw[5]      = {65536, 16384, 4096, 1024, 256};
__constant__ int c_lghw[5]    = {16, 14, 12, 10, 8};
__constant__ int c_K[5]       = {1000, 1000, 1000, 1000, 768};
__constant__ int c_levNOff[5] = {0, 196608, 245760, 258048, 261120};
__constant__ int c_selOff[5]  = {0, 1000, 2000, 3000, 4000};

__device__ __forceinline__ u32 monokey(float f) {
  u32 u = __float_as_uint(f);
  return (u & 0x80000000u) ? ~u : (u | 0x80000000u);
}
__device__ __forceinline__ float inv_monokey(u32 k) {
  return __uint_as_float((k & 0x80000000u) ? (k ^ 0x80000000u) : ~k);
}
__device__ __forceinline__ u64 lanemask_lt(int lane) {
  return lane ? ((~0ULL) >> (64 - lane)) : 0ULL;
}

// Bitwise replica of XLA CPU logistic (verified bit-exact R1/R2, absmax 0.0).
__device__ float sigmoid_xla(float x) {
  #pragma clang fp contract(off)
  float h = 0.5f * x;
  float hc = fminf(fmaxf(h, -7.90531110763549805f), 7.90531110763549805f);
  float x2 = hc * hc;
  float p = -2.76076847742355e-16f;
  p = p * x2 + 2.00018790482477e-13f;
  p = p * x2 + -8.60467152213735e-11f;
  p = p * x2 + 5.12229709037114e-08f;
  p = p * x2 + 1.48572235717979e-05f;
  p = p * x2 + 6.37261928875436e-04f;
  p = p * x2 + 4.89352455891786e-03f;
  p = hc * p;
  float q = 1.19825839466702e-06f;
  q = q * x2 + 1.18534705686654e-04f;
  q = q * x2 + 2.26843463243900e-03f;
  q = q * x2 + 4.89352518554385e-03f;
  float t = (fabsf(h) < 0.0004f) ? h : (p / q);
  return 0.5f + 0.5f * t;
}

__device__ void decode_box(float4 anc, float dx, float dy, float dw, float dh,
                           float& x0, float& y0, float& x1, float& y1, bool& keep) {
  #pragma clang fp contract(off)
  float aw = anc.z - anc.x;
  float ah = anc.w - anc.y;
  float ax = anc.x + 0.5f * aw;
  float ay = anc.y + 0.5f * ah;
  float dwc = fminf(dw, 4.135166556742356f);
  float dhc = fminf(dh, 4.135166556742356f);
  float px = dx * aw + ax;
  float py = dy * ah + ay;
  float pw = expf(dwc) * aw;
  float ph = expf(dhc) * ah;
  x0 = px - 0.5f * pw;
  y0 = py - 0.5f * ph;
  x1 = px + 0.5f * pw;
  y1 = py + 0.5f * ph;
  x0 = fminf(fmaxf(x0, 0.0f), 1024.0f);
  y0 = fminf(fmaxf(y0, 0.0f), 1024.0f);
  x1 = fminf(fmaxf(x1, 0.0f), 1024.0f);
  y1 = fminf(fmaxf(y1, 0.0f), 1024.0f);
  keep = ((x1 - x0) >= 1.0f) && ((y1 - y0) >= 1.0f);
}

// Exact (inter/denom > 0.7f) under IEEE f32 div; early-out safe (quotient
// <= 0.65 cannot round across 0.7f).
__device__ __forceinline__ bool iou_gt(float4 a, float aa, float4 b, float ba) {
  #pragma clang fp contract(off)
  float w = fmaxf(fminf(a.z, b.z) - fmaxf(a.x, b.x), 0.0f);
  float h = fmaxf(fminf(a.w, b.w) - fmaxf(a.y, b.y), 0.0f);
  float inter = w * h;
  float denom = aa + ba - inter + 1e-9f;
  if (inter <= 0.65f * denom) return false;
  return (inter / denom) > 0.7f;
}

// Parallel suffix-scan threshold find over a 2-copy histogram (stride 2048).
// Writes shOut[0]=bin, shOut[1]=count-above-bin. Uniform call; 2 barriers.
__device__ __forceinline__ void find_thresh(const u32* histF, int nb, u32 K,
                                            u32 cAbove, u32* wsum, u32* wsuf,
                                            u32* shOut, int tid) {
  const int lane = tid & 63, w = tid >> 6;
  u32 h0, h1;
  if (nb == 2048) {
    int b0 = 2 * tid, b1 = b0 + 1;
    h0 = histF[b0] + histF[2048 + b0];
    h1 = histF[b1] + histF[2048 + b1];
  } else {
    h0 = histF[tid] + histF[2048 + tid];
    h1 = 0u;
  }
  u32 x = h0 + h1;
  #pragma unroll
  for (int off = 1; off < 64; off <<= 1) {
    u32 v = __shfl_down(x, off);
    if (lane + off < 64) x += v;
  }
  if (lane == 0) wsum[w] = x;
  __syncthreads();
  if (tid == 0) {
    u32 acc = 0;
    wsuf[16] = 0u;
    for (int q = 15; q >= 0; --q) { acc += wsum[q]; wsuf[q] = acc; }
  }
  __syncthreads();
  u32 SUF0 = x + wsuf[w + 1];
  if (cAbove + SUF0 >= K && cAbove + SUF0 - h0 < K) {
    shOut[0] = (nb == 2048) ? (u32)(2 * tid) : (u32)tid;
    shOut[1] = cAbove + SUF0 - h0;
  }
  if (nb == 2048) {
    u32 SUF1 = SUF0 - h0;
    if (cAbove + SUF1 >= K && cAbove + SUF1 - h1 < K) {
      shOut[0] = (u32)(2 * tid + 1);
      shOut[1] = cAbove + SUF1 - h1;
    }
  }
  __syncthreads();
}

__global__ __launch_bounds__(1024) void k_select(Ptrs p, u64* __restrict__ keysC,
                                                 u32* __restrict__ cntOut,
                                                 float4* __restrict__ boxesWs) {
  const int l = (int)(blockIdx.x % 5);
  const int b = (int)(blockIdx.x / 5);
  const int hw = c_hw[l], lghw = c_lghw[l];
  const int n = 3 * hw, K = c_K[l];
  const int tid = threadIdx.x;
  const int lane = tid & 63;
  const float* base = p.cls[l] + (size_t)b * (size_t)n;
  const float4* base4 = (const float4*)base;
  const int n4 = n >> 2;

  __shared__ u32 histF[4096];  // 2 copies x 2048 bins
  __shared__ __align__(16) u64 slots[1024];
  __shared__ __align__(16) u64 cand[CANDCAP];
  __shared__ u32 tieN[1024];
  __shared__ u32 sh[4];
  __shared__ u32 wsum[16], wsuf[17];
  __shared__ u32 candCnt;

  slots[tid] = 0ULL;
  u32* hc = &histF[((tid >> 6) & 1) * 2048];

  if (K >= n) {
    // level 4: all elements selected; order fixed by the sort below.
    if (tid < n) {
      u32 mk = monokey(base[tid]);
      int a = tid >> lghw, cell = tid & (hw - 1);
      u32 nloc = (u32)(cell * 3 + a);
      slots[tid] = (((u64)mk) << 32) | (0xFFFFFFFFu - nloc);
    }
    __syncthreads();
  } else {
    // ---- pass 0: full scan, 2048-bin hist on top 11 bits ----
    for (int i = tid; i < 4096; i += 1024) histF[i] = 0u;
    __syncthreads();
    for (int i = tid; i < n4; i += 1024) {
      float4 v = base4[i];
      float fv[4] = {v.x, v.y, v.z, v.w};
      #pragma unroll
      for (int c = 0; c < 4; ++c) atomicAdd(&hc[monokey(fv[c]) >> 21], 1u);
    }
    __syncthreads();
    find_thresh(histF, 2048, (u32)K, 0u, wsum, wsuf, sh, tid);
    const u32 b0 = sh[0];
    const u32 cA0 = sh[1];
    __syncthreads();

    // ---- pass 1: full scan; mid-bit hist within b0; capture bin>=b0 ----
    for (int i = tid; i < 4096; i += 1024) histF[i] = 0u;
    if (tid == 0) candCnt = 0u;
    __syncthreads();
    for (int i = tid; i < n4; i += 1024) {
      float4 v = base4[i];
      float fv[4] = {v.x, v.y, v.z, v.w};
      #pragma unroll
      for (int c = 0; c < 4; ++c) {
        u32 mk = monokey(fv[c]);
        u32 bin = mk >> 21;
        if (bin == b0) atomicAdd(&hc[(mk >> 10) & 0x7FFu], 1u);
        bool cc = (bin >= b0);
        u64 cb = __ballot(cc);
        if (cc) {
          int pe = 4 * i + c;
          int a = pe >> lghw, cell = pe & (hw - 1);
          u32 nloc = (u32)(cell * 3 + a);
          int leader = __builtin_ctzll(cb);
          u32 wcnt = (u32)__popcll(cb);
          u32 bs;
          if (lane == leader) bs = atomicAdd(&candCnt, wcnt);
          bs = __shfl(bs, leader);
          u32 u = bs + (u32)__popcll(cb & lanemask_lt(lane));
          if (u < CANDCAP) cand[u] = (((u64)mk) << 32) | nloc;
        }
      }
    }
    __syncthreads();
    find_thresh(histF, 2048, (u32)K, cA0, wsum, wsuf, sh, tid);
    const u32 b1 = sh[0];
    const u32 cA1 = sh[1];
    const u32 prefix22 = (b0 << 11) | b1;
    const u32 nCand = candCnt;
    __syncthreads();

    u32 threshKey;
    if (nCand <= CANDCAP) {
      // ---- pass 2 + selection over LDS candidates ----
      for (int i = tid; i < 4096; i += 1024) histF[i] = 0u;
      __syncthreads();
      for (int i = tid; i < (int)nCand; i += 1024) {
        u32 mk = (u32)(cand[i] >> 32);
        if ((mk >> 10) == prefix22) atomicAdd(&hc[mk & 0x3FFu], 1u);
      }
      __syncthreads();
      find_thresh(histF, 1024, (u32)K, cA1, wsum, wsuf, sh, tid);
      threshKey = (prefix22 << 10) | sh[0];
      if (tid == 0) { sh[2] = 0u; sh[3] = 0u; }
      __syncthreads();
      for (int i = tid; i < (int)nCand; i += 1024) {
        u64 e = cand[i];
        u32 mk = (u32)(e >> 32);
        u32 nloc = (u32)(e & 0xFFFFFFFFull);
        bool gt = (mk > threshKey);
        u64 gb = __ballot(gt);
        if (gt) {
          int leader = __builtin_ctzll(gb);
          u32 wcnt = (u32)__popcll(gb);
          u32 bs;
          if (lane == leader) bs = atomicAdd(&sh[2], wcnt);
          bs = __shfl(bs, leader);
          u32 s = bs + (u32)__popcll(gb & lanemask_lt(lane));
          slots[s] = (((u64)mk) << 32) | (0xFFFFFFFFu - nloc);
        } else if (mk == threshKey) {
          u32 tt = atomicAdd(&sh[3], 1u);
          if (tt < 1024u) tieN[tt] = nloc;
        }
      }
      __syncthreads();
    } else {
      // ---- fallback (cand overflow): global pass 2 + global selection ----
      for (int i = tid; i < 4096; i += 1024) histF[i] = 0u;
      __syncthreads();
      for (int i = tid; i < n4; i += 1024) {
        float4 v = base4[i];
        float fv[4] = {v.x, v.y, v.z, v.w};
        #pragma unroll
        for (int c = 0; c < 4; ++c) {
          u32 mk = monokey(fv[c]);
          if ((mk >> 10) == prefix22) atomicAdd(&hc[mk & 0x3FFu], 1u);
        }
      }
      __syncthreads();
      find_thresh(histF, 1024, (u32)K, cA1, wsum, wsuf, sh, tid);
      threshKey = (prefix22 << 10) | sh[0];
      if (tid == 0) { sh[2] = 0u; sh[3] = 0u; }
      __syncthreads();
      for (int i = tid; i < n4; i += 1024) {
        float4 v = base4[i];
        float fv[4] = {v.x, v.y, v.z, v.w};
        #pragma unroll
        for (int c = 0; c < 4; ++c) {
          u32 mk = monokey(fv[c]);
          if (mk >= threshKey) {
            int pe = 4 * i + c;
            int a = pe >> lghw, cell = pe & (hw - 1);
            u32 nloc = (u32)(cell * 3 + a);
            if (mk > threshKey) {
              u32 s = atomicAdd(&sh[2], 1u);
              slots[s] = (((u64)mk) << 32) | (0xFFFFFFFFu - nloc);
            } else {
              u32 tt = atomicAdd(&sh[3], 1u);
              if (tt < 1024u) tieN[tt] = nloc;
            }
          }
        }
      }
      __syncthreads();
    }
    // tie fill (need is typically 1-3)
    if (tid == 0) {
      int cnt = (int)sh[2];
      int need = K - cnt;
      int tc = (int)sh[3];
      if (tc > 1024) tc = 1024;
      for (int s = 0; s < need; ++s) {
        u32 best = 0xFFFFFFFFu;
        int bj = -1;
        for (int i2 = 0; i2 < tc; ++i2) {
          u32 v = tieN[i2];
          if (v < best) { best = v; bj = i2; }
        }
        if (bj < 0) break;
        tieN[bj] = 0xFFFFFFFFu;
        slots[cnt + s] = (((u64)threshKey) << 32) | (0xFFFFFFFFu - best);
      }
    }
    __syncthreads();
  }

  // ---- hybrid bitonic sort, 1024 desc by (logitKey desc, nloc asc) ----
  u64 v = slots[tid];
  for (int kk = 2; kk <= 1024; kk <<= 1) {
    for (int j = kk >> 1; j > 0; j >>= 1) {
      u64 pv;
      if (j >= 64) {
        __syncthreads();
        slots[tid] = v;
        __syncthreads();
        pv = slots[tid ^ j];
      } else {
        pv = __shfl_xor(v, j);
      }
      bool takeMax = (((tid & kk) == 0) == ((tid & j) == 0));
      v = takeMax ? ((pv > v) ? pv : v) : ((pv < v) ? pv : v);
    }
  }
  // v is the element at sorted rank `tid`.

  // ---- decode + sigmoid + compacted key emit ----
  const float4* anc4 = (const float4*)p.anc;
  const float* bxbase = p.box[l];
  const int levN = c_levNOff[l], selO = c_selOff[l];
  bool keepf = false;
  u64 outKey = 0ULL;
  if (tid < K && v != 0ULL) {
    u32 mk = (u32)(v >> 32);
    u32 nloc = 0xFFFFFFFFu - (u32)(v & 0xFFFFFFFFull);
    float logit = inv_monokey(mk);
    int cell = (int)(nloc / 3u);
    int a = (int)(nloc - 3u * (u32)cell);
    const float* dptr = bxbase + (((size_t)(b * 12 + a * 4)) << lghw) + (size_t)cell;
    float dx = dptr[0];
    float dy = dptr[(size_t)hw];
    float dw = dptr[(size_t)2 * (size_t)hw];
    float dh = dptr[(size_t)3 * (size_t)hw];
    float4 anc = anc4[levN + (int)nloc];
    float x0, y0, x1, y1;
    bool keep;
    decode_box(anc, dx, dy, dw, dh, x0, y0, x1, y1, keep);
    int pos = selO + tid;
    boxesWs[(size_t)b * KSUM + (size_t)pos] = make_float4(x0, y0, x1, y1);
    if (keep) {
      float prob = sigmoid_xla(logit);
      keepf = true;
      outKey = (((u64)__float_as_uint(prob)) << 32) | (0xFFFFFFFFu - (u32)pos);
    }
  }
  // ballot prefix-scan compaction (preserves rank order => segment sorted)
  u64 bal = __ballot(keepf);
  if (lane == 0) wsum[tid >> 6] = (u32)__popcll(bal);
  __syncthreads();
  if (tid < 16) {
    u32 xx = wsum[tid], orig = xx;
    #pragma unroll
    for (int off = 1; off < 16; off <<= 1) {
      u32 vv = __shfl_up(xx, off);
      if (tid >= off) xx += vv;
    }
    wsuf[tid] = xx - orig;        // exclusive wave offset
    if (tid == 15) cntOut[b * 5 + l] = xx;  // total keeps
  }
  __syncthreads();
  if (keepf) {
    u32 cidx = wsuf[tid >> 6] + (u32)__popcll(bal & lanemask_lt(lane));
    keysC[((size_t)(b * 5 + l)) * 1000 + cidx] = outKey;
  }
}

__global__ __launch_bounds__(1024) void k_nms(const u64* __restrict__ keysC,
                                              const u32* __restrict__ cnt,
                                              const float4* __restrict__ boxesWs,
                                              float* __restrict__ out) {
  const int b = blockIdx.x;
  const int tid = threadIdx.x;
  __shared__ __align__(16) u64 keys[5000];        // 40000 B
  __shared__ __align__(16) float4 keptBox[1000];  // 16000 B
  __shared__ __align__(16) float4 chunkBox[128];
  __shared__ float chunkArea[128];
  __shared__ float chunkProb[128];
  __shared__ u32 chunkAlive[128];
  __shared__ u64 suppBy[256];
  __shared__ u64 sAB[2];
  __shared__ u32 scnt[5];

  if (tid < 5) scnt[tid] = cnt[b * 5 + tid];
  __syncthreads();
  const int N = (int)(scnt[0] + scnt[1] + scnt[2] + scnt[3] + scnt[4]);

  // load the 5 sorted segments at fixed 1000-stride offsets
  for (int i = tid; i < 5000; i += 1024) {
    int l = i / 1000, ii = i - l * 1000;
    if (ii < (int)scnt[l]) keys[i] = keysC[((size_t)(b * 5 + l)) * 1000 + ii];
  }
  __syncthreads();

  // ---- 5-way merge by rank: rank = own idx + sum of count-greater ----
  u64 myKey[5];
  int myRank[5];
  #pragma unroll
  for (int q = 0; q < 5; ++q) {
    int s = tid + q * 1024;
    myRank[q] = -1;
    myKey[q] = 0ULL;
    if (s < 5000) {
      int l = s / 1000, ii = s - l * 1000;
      if (ii < (int)scnt[l]) {
        u64 e = keys[s];
        int rank = ii;
        #pragma unroll
        for (int l2 = 0; l2 < 5; ++l2) {
          if (l2 == l) continue;
          int base2 = l2 * 1000;
          int lo = 0, hi = (int)scnt[l2];
          while (lo < hi) {
            int mid = (lo + hi) >> 1;
            if (keys[base2 + mid] > e) lo = mid + 1; else hi = mid;
          }
          rank += lo;  // count of strictly-greater (keys unique)
        }
        myKey[q] = e;
        myRank[q] = rank;
      }
    }
  }
  __syncthreads();  // all reads done; now overwrite in place
  #pragma unroll
  for (int q = 0; q < 5; ++q)
    if (myRank[q] >= 0) keys[myRank[q]] = myKey[q];
  __syncthreads();

  // ---- chunked greedy NMS == the 1000-step argmax/suppress scan ----
  int m = 0;
  for (int cs = 0; cs < N && m < 1000; cs += 128) {
    if (tid < 128) {
      int idx = cs + tid;
      float4 bx = make_float4(0.f, 0.f, 0.f, 0.f);
      float ar = 0.f, pr = 0.f;
      u32 alive = 0u;
      if (idx < N) {
        u64 e = keys[idx];
        u32 r = 0xFFFFFFFFu - (u32)(e & 0xFFFFFFFFull);
        bx = boxesWs[(size_t)b * KSUM + r];
        pr = __uint_as_float((u32)(e >> 32));
        {
          #pragma clang fp contract(off)
          ar = (bx.z - bx.x) * (bx.w - bx.y);
        }
        alive = 1u;
      }
      chunkBox[tid] = bx;
      chunkArea[tid] = ar;
      chunkProb[tid] = pr;
      chunkAlive[tid] = alive;
    }
    if (tid < 256) suppBy[tid] = 0ULL;
    __syncthreads();

    // A: chunk vs kept (8 threads/box, pipelined |=)
    {
      int i0 = tid & 127;
      int sl = tid >> 7;
      float4 my = chunkBox[i0];
      float myA = chunkArea[i0];
      bool supp = false;
      #pragma unroll 4
      for (int i = sl; i < m; i += 8) {
        float4 kb = keptBox[i];
        float ka;
        {
          #pragma clang fp contract(off)
          ka = (kb.z - kb.x) * (kb.w - kb.y);
        }
        supp = supp | iou_gt(kb, ka, my, myA);
      }
      if (supp) chunkAlive[i0] = 0u;
    }
    // B: intra-chunk suppressor masks (suppBy[i] bit j: j<i suppresses i)
    for (int pI = tid; pI < 16384; pI += 1024) {
      int i = pI >> 7;
      int j = pI & 127;
      if (j < i) {
        if (iou_gt(chunkBox[j], chunkArea[j], chunkBox[i], chunkArea[i]))
          atomicOr(&suppBy[i * 2 + (j >> 6)], 1ULL << (j & 63));
      }
    }
    __syncthreads();

    // C: wave-ballot greedy resolution, skipping non-suppressor bits
    if (tid < 64) {
      bool aliveLo = chunkAlive[tid] != 0u;
      bool aliveHi = chunkAlive[64 + tid] != 0u;
      u64 sLL = suppBy[tid * 2];
      u64 sHL = suppBy[(64 + tid) * 2];
      u64 sHH = suppBy[(64 + tid) * 2 + 1];
      u64 uLo = sLL;
      #pragma unroll
      for (int off = 1; off < 64; off <<= 1) uLo |= __shfl_xor(uLo, off);
      u64 rem = uLo;
      while (rem) {
        int k = __builtin_ctzll(rem);
        rem &= rem - 1ULL;
        u64 A = __ballot(aliveLo);
        if (((A >> k) & 1ULL) && ((sLL >> k) & 1ULL)) aliveLo = false;
      }
      u64 A0 = __ballot(aliveLo);
      if (sHL & A0) aliveHi = false;
      u64 uHi = sHH;
      #pragma unroll
      for (int off = 1; off < 64; off <<= 1) uHi |= __shfl_xor(uHi, off);
      rem = uHi;
      while (rem) {
        int k = __builtin_ctzll(rem);
        rem &= rem - 1ULL;
        u64 A = __ballot(aliveHi);
        if (((A >> k) & 1ULL) && ((sHH >> k) & 1ULL)) aliveHi = false;
      }
      u64 A1 = __ballot(aliveHi);
      if (tid == 0) { sAB[0] = A0; sAB[1] = A1; }
    }
    __syncthreads();

    // D: emit kept boxes in order
    u64 A0 = sAB[0], A1 = sAB[1];
    int total = __popcll(A0) + __popcll(A1);
    if (tid < 128) {
      bool kept = (tid < 64) ? ((A0 >> tid) & 1ULL) : ((A1 >> (tid - 64)) & 1ULL);
      if (kept) {
        int rank = (tid < 64)
                       ? __popcll(A0 & ((1ULL << tid) - 1ULL))
                       : (__popcll(A0) + __popcll(A1 & ((1ULL << (tid - 64)) - 1ULL)));
        int g = m + rank;
        if (g < 1000) {
          keptBox[g] = chunkBox[tid];
          ((float4*)out)[b * 1000 + g] = chunkBox[tid];
          out[64000 + b * 1000 + g] = chunkProb[tid];
        }
      }
    }
    m += total;
    if (m > 1000) m = 1000;
    __syncthreads();
  }

  // pad: box = 0, score = NEG
  for (int g = m + tid; g < 1000; g += 1024) {
    ((float4*)out)[b * 1000 + g] = make_float4(0.f, 0.f, 0.f, 0.f);
    out[64000 + b * 1000 + g] = NEGF;
  }
}

extern "C" void kernel_launch(void* const* d_in, const int* in_sizes, int n_in,
                              void* d_out, int out_size, void* d_ws, size_t ws_size,
                              hipStream_t stream) {
  bool interleaved = (in_sizes[1] == 16 * 12 * 256 * 256);
  Ptrs p;
  for (int l = 0; l < 5; ++l) {
    p.cls[l] = (const float*)d_in[interleaved ? (2 * l) : l];
    p.box[l] = (const float*)d_in[interleaved ? (2 * l + 1) : (5 + l)];
  }
  p.anc = (const float*)d_in[10];

  // ws layout: keysC [16*5*1000 u64] = 640000 B | cnt [80 u32] | boxesWs
  u64* keysC = (u64*)d_ws;
  u32* cntW = (u32*)((char*)d_ws + 640000);
  float4* boxesWs = (float4*)((char*)d_ws + 640512);

  k_select<<<dim3(NBATCH * 5), dim3(1024), 0, stream>>>(p, keysC, cntW, boxesWs);
  k_nms<<<dim3(NBATCH), dim3(1024), 0, stream>>>(keysC, cntW, boxesWs, (float*)d_out);
}